// Round 1
// 285.815 us; speedup vs baseline: 1.0618x; 1.0618x over previous
//
#include <hip/hip_runtime.h>
#include <cstdint>
#include <cstddef>

#define N_NODES 50000
#define E_EDGES 800000
#define IN_F    128
#define PCOLS   512   // Pb cols: [0,96) Y0 | [96,192) Zpre | [192,288) Zblk | [288,480) Zpost | pad

typedef unsigned short ushortT;
typedef unsigned int   uintT;
typedef __attribute__((ext_vector_type(8))) short s8v;   // 8 bf16 (4 VGPR)
typedef __attribute__((ext_vector_type(4))) float f4v;   // 4 fp32 acc
typedef __attribute__((ext_vector_type(2))) float f2v;   // packed fp32 pair (v_pk_add_f32 target)

__device__ __forceinline__ float bflo(uintT u){ union{uintT i;float f;}c; c.i=u<<16; return c.f; }
__device__ __forceinline__ float bfhi(uintT u){ union{uintT i;float f;}c; c.i=u&0xFFFF0000u; return c.f; }
__device__ __forceinline__ ushortT f2bfu(float f){
    union{float f;uintT u;}c; c.f=f;
    uintT r = c.u + 0x7FFF + ((c.u>>16)&1);
    return (ushortT)(r>>16);
}
__device__ __forceinline__ uintT pack2(float a, float b){
    return (uintT)f2bfu(a) | ((uintT)f2bfu(b) << 16);
}

// ---------- prep1: pack weights + convert data + row_ptr + dummy-row zero ----------
// grid = 800000 threads exactly (N*IN_F/8)
__global__ void prep1(const float* __restrict__ A,
                      const float* __restrict__ Wp,  const float* __restrict__ bp,
                      const float* __restrict__ Tp,  const float* __restrict__ bTp,
                      const float* __restrict__ Tb,  const float* __restrict__ bTb,
                      const float* __restrict__ Tpo, const float* __restrict__ bTpo,
                      const float* __restrict__ Wpost,
                      const int* __restrict__ tgt,
                      ushortT* __restrict__ Wb, float* __restrict__ bcat,
                      float2* __restrict__ Wp2,
                      ushortT* __restrict__ Ab, int* __restrict__ row_ptr,
                      ushortT* __restrict__ Pb, ushortT* __restrict__ rb1,
                      ushortT* __restrict__ rb2)
{
    int gid = blockIdx.x * 256 + threadIdx.x;
    {
        size_t off = (size_t)gid * 8;
        float4 v0 = *(const float4*)(A + off);
        float4 v1 = *(const float4*)(A + off + 4);
        uint4 u;
        u.x = pack2(v0.x, v0.y); u.y = pack2(v0.z, v0.w);
        u.z = pack2(v1.x, v1.y); u.w = pack2(v1.z, v1.w);
        *(uint4*)(Ab + off) = u;
    }
    if (gid < IN_F * PCOLS) {
        int k = gid >> 9;
        int c = gid & 511;
        float v;
        if      (c < 96)  v = Wp [k*96  + c];
        else if (c < 192) v = Tp [k*96  + (c-96)];
        else if (c < 288) v = Tb [k*96  + (c-192)];
        else if (c < 480) v = Tpo[k*192 + (c-288)];
        else              v = 0.f;
        Wb[(size_t)c*IN_F + k] = f2bfu(v);
        if (k == 0) {
            float b;
            if      (c < 96)  b = bp  [c];
            else if (c < 192) b = bTp [c-96];
            else if (c < 288) b = bTb [c-192];
            else if (c < 480) b = bTpo[c-288];
            else              b = 0.f;
            bcat[c] = b;
        }
        if (gid < 3*16*64) {   // Wp2[(w*16+i2)*64+j] = (Wpost[w][2i2][j], Wpost[w][2i2+1][j])
            int w = gid >> 10, r = gid & 1023;
            int i2 = r >> 6, j = r & 63;
            Wp2[gid] = make_float2(Wpost[(w*32 + 2*i2)*64 + j],
                                   Wpost[(w*32 + 2*i2 + 1)*64 + j]);
        }
    }
    if (gid < 96) {   // dummy gather row (node N) = 0 in every gather source
        Pb [(size_t)N_NODES*PCOLS + gid] = 0;
        rb1[(size_t)N_NODES*96   + gid] = 0;
        rb2[(size_t)N_NODES*96   + gid] = 0;
    }
    if (gid <= N_NODES) {
        int lo = 0, hi = E_EDGES;
        while (lo < hi) {
            int mid = (lo + hi) >> 1;
            if (tgt[mid] < gid) lo = mid + 1; else hi = mid;
        }
        row_ptr[gid] = lo;
    }
}

// ---------- MFMA GEMM: Pb[M,512] = bf16(Ab[M,128] @ Wb^T + bcat) ----------
__global__ __launch_bounds__(256, 2) void gemm_mfma(const ushortT* __restrict__ Ab,
                                                    const ushortT* __restrict__ Wb,
                                                    const float* __restrict__ bcat,
                                                    ushortT* __restrict__ Pb, int M)
{
    __shared__ ushortT Asl[128][72];
    __shared__ ushortT Bsl[128][72];
    int tid = threadIdx.x;
    int nb = blockIdx.x * 128;
    int mb = blockIdx.y * 128;
    int wv = tid >> 6, lane = tid & 63;
    int wm = wv >> 1, wn = wv & 1;
    int cl = lane & 15, q = lane >> 4;

    f4v acc[4][4];
    #pragma unroll
    for (int i = 0; i < 4; ++i)
        #pragma unroll
        for (int j = 0; j < 4; ++j) acc[i][j] = (f4v)0.f;

    for (int kt = 0; kt < IN_F; kt += 64) {
        if (kt) __syncthreads();
        #pragma unroll
        for (int r = 0; r < 4; ++r) {
            int idx = tid + 256*r;
            int row = idx >> 3, qq = idx & 7;
            int gm = mb + row;
            uint4 v = make_uint4(0,0,0,0);
            if (gm < M) v = *(const uint4*)(Ab + (size_t)gm*IN_F + kt + qq*8);
            *(uint4*)(&Asl[row][qq*8]) = v;
        }
        #pragma unroll
        for (int r = 0; r < 4; ++r) {
            int idx = tid + 256*r;
            int row = idx >> 3, qq = idx & 7;
            uint4 v = *(const uint4*)(Wb + (size_t)(nb+row)*IN_F + kt + qq*8);
            *(uint4*)(&Bsl[row][qq*8]) = v;
        }
        __syncthreads();
        #pragma unroll
        for (int ks = 0; ks < 2; ++ks) {
            int ko = ks*32 + q*8;
            s8v af[4], bf[4];
            #pragma unroll
            for (int mt = 0; mt < 4; ++mt)
                af[mt] = *(const s8v*)(&Asl[wm*64 + mt*16 + cl][ko]);
            #pragma unroll
            for (int nt = 0; nt < 4; ++nt)
                bf[nt] = *(const s8v*)(&Bsl[wn*64 + nt*16 + cl][ko]);
            #pragma unroll
            for (int mt = 0; mt < 4; ++mt)
                #pragma unroll
                for (int nt = 0; nt < 4; ++nt)
                    acc[mt][nt] = __builtin_amdgcn_mfma_f32_16x16x32_bf16(af[mt], bf[nt], acc[mt][nt], 0, 0, 0);
        }
    }

    #pragma unroll
    for (int nt = 0; nt < 4; ++nt) {
        int gn = nb + wn*64 + nt*16 + cl;
        float bv = bcat[gn];
        #pragma unroll
        for (int mt = 0; mt < 4; ++mt) {
            int gm0 = mb + wm*64 + mt*16 + q*4;
            #pragma unroll
            for (int r = 0; r < 4; ++r) {
                int gm = gm0 + r;
                if (gm < M) Pb[(size_t)gm*PCOLS + gn] = f2bfu(acc[mt][nt][r] + bv);
            }
        }
    }
}

// ===== gather core: 16-deep windows; scalar byte-offset addressing + packed adds =====
// sv holds PRE-SCALED byte offsets (row*STRB). (Xb + off) is wave-uniform -> saddr form;
// 4*pL is the per-lane constant voffset. STRB = gather-source row stride in BYTES.
#define GATHER96(Xb, lo, deg, sv, pL, STRB, sx, sy)                               \
    float sx, sy;                                                                 \
    {                                                                             \
        f2v c0={0.f,0.f}, c1={0.f,0.f}, c2={0.f,0.f}, c3={0.f,0.f};               \
        int dmax = deg < 64 ? deg : 64;                                           \
        _Pragma("unroll 1")                                                       \
        for (int w_ = 0; w_ < dmax; w_ += 16) {                                   \
            uintT u[16];                                                          \
            _Pragma("unroll")                                                     \
            for (int kk = 0; kk < 16; ++kk) {                                     \
                int off = __builtin_amdgcn_readlane(sv, w_ + kk);                 \
                const char* rp = (const char*)(Xb) + off;                         \
                u[kk] = *(const uintT*)(rp + 4*pL);                               \
            }                                                                     \
            _Pragma("unroll")                                                     \
            for (int kk = 0; kk < 16; ++kk) {                                     \
                f2v v_; v_.x = bflo(u[kk]); v_.y = bfhi(u[kk]);                   \
                switch (kk & 3) {                                                 \
                    case 0: c0 += v_; break;                                      \
                    case 1: c1 += v_; break;                                      \
                    case 2: c2 += v_; break;                                      \
                    default:c3 += v_; break;                                      \
                }                                                                 \
            }                                                                     \
        }                                                                         \
        if (deg > 64) {                                                           \
            _Pragma("unroll 1")                                                   \
            for (int j_ = lo + 64; j_ < lo + deg; ++j_) {                         \
                int off = src[j_] * (STRB);                                       \
                const char* rp = (const char*)(Xb) + off;                         \
                uintT u0 = *(const uintT*)(rp + 4*pL);                            \
                f2v v_; v_.x = bflo(u0); v_.y = bfhi(u0);                         \
                c0 += v_;                                                         \
            }                                                                     \
        }                                                                         \
        f2v cs_ = (c0 + c1) + (c2 + c3);                                          \
        sx = cs_.x; sy = cs_.y;                                                   \
    }

// per-lane gather slot from raw src: lane<deg ? src[lo+lane] : dummy row N
#define MAKE_SV(lo, deg, lane, STRB, sv)                                          \
    int sv;                                                                       \
    {                                                                             \
        int e_ = (lo) + (lane);                                                   \
        if (e_ > E_EDGES - 1) e_ = E_EDGES - 1;                                   \
        int sn_ = src[e_];                                                        \
        sv = ((lane) < (deg) ? sn_ : N_NODES) * (STRB);                           \
    }

// ---------- layer 1: rb1 = bf16(relu(Lap(Y0) + Zpre)), wave per node ----------
// own-x, Z and the gather all come from bf16 Pb (row stride 1024 B, cols 0..95 = Y0)
__global__ __launch_bounds__(256) void lap1(
    const ushortT* __restrict__ Pb,
    const int* __restrict__ src, const int* __restrict__ row_ptr,
    ushortT* __restrict__ rb1)
{
    int lane = threadIdx.x & 63;
    int t  = __builtin_amdgcn_readfirstlane((blockIdx.x << 2) + (threadIdx.x >> 6));
    int lo = __builtin_amdgcn_readfirstlane(row_ptr[t]);
    int deg = __builtin_amdgcn_readfirstlane(row_ptr[t+1]) - lo;
    int pL = lane < 48 ? lane : 0;
    MAKE_SV(lo, deg, lane, 2*PCOLS, sv)                    // Pb row = 1024 B
    uintT ux = *(const uintT*)(Pb + (size_t)t*PCOLS + 2*pL);        // Y0 cols 2pL,2pL+1
    uintT zu = *(const uintT*)(Pb + (size_t)t*PCOLS + 96 + 2*pL);   // Zpre

    GATHER96(Pb, lo, deg, sv, pL, 2*PCOLS, sx, sy)

    float inv = deg > 0 ? 1.f/(float)deg : 0.f;
    float mf  = deg > 0 ? 1.f : 0.f;
    if (lane < 48) {
        float ox = fmaxf(mf*bflo(ux) - sx*inv + bflo(zu), 0.f);
        float oy = fmaxf(mf*bfhi(ux) - sy*inv + bfhi(zu), 0.f);
        *(uintT*)(rb1 + (size_t)t*96 + 2*pL) = pack2(ox, oy);
    }
}

// ---------- layer 2: rb2 = bf16(relu(Lap(rb1)@W_blk + Zblk)) ----------
// persistent: 3125 blocks x 4 iters; weights staged once per block
__global__ __launch_bounds__(256) void lap2(
    const ushortT* __restrict__ Xb,    // rb1 [N+1,96]
    const ushortT* __restrict__ Pb,    // Zblk = cols 192..287
    const int* __restrict__ src, const int* __restrict__ row_ptr,
    const float* __restrict__ Wblk,    // [3][32][32] flat
    ushortT* __restrict__ rb2)
{
    __shared__ float wS[3*32*32];
    for (int i = threadIdx.x; i < 3072; i += 256) wS[i] = Wblk[i];
    __syncthreads();

    int lane = threadIdx.x & 63;
    int wvw  = threadIdx.x >> 6;
    int pL = lane < 48 ? lane : 0;
    int w  = pL >> 4;            // group (uniform per 16-lane slab)
    int jj = pL & 15;            // out pair index within group
    const float2* wc = ((const float2*)wS) + (w*512 + jj);   // &W[w][0][2jj]

    #pragma unroll 1
    for (int it = 0; it < 4; ++it) {
        int t  = __builtin_amdgcn_readfirstlane(blockIdx.x*16 + it*4 + wvw);
        int lo = __builtin_amdgcn_readfirstlane(row_ptr[t]);
        int deg = __builtin_amdgcn_readfirstlane(row_ptr[t+1]) - lo;
        MAKE_SV(lo, deg, lane, 192, sv)
        uintT ux = *(const uintT*)(Xb + (size_t)t*96 + 2*pL);
        uintT zu = *(const uintT*)(Pb + (size_t)t*PCOLS + 192 + 2*pL);

        GATHER96(Xb, lo, deg, sv, pL, 192, sx, sy)

        float inv = deg > 0 ? 1.f/(float)deg : 0.f;
        float mf  = deg > 0 ? 1.f : 0.f;
        float Lx = mf*bflo(ux) - sx*inv;    // Lap feat 2pL
        float Ly = mf*bfhi(ux) - sy*inv;    // Lap feat 2pL+1

        // conv (no bias): out channels (2pL, 2pL+1), inputs = group-w feats via shfl
        float accx = 0.f, accy = 0.f;
        #pragma unroll
        for (int d = 0; d < 16; ++d) {
            int sl = w*16 + d;
            float ax = __shfl(Lx, sl);      // feat 32w+2d
            float ay = __shfl(Ly, sl);      // feat 32w+2d+1
            float2 wa = wc[(2*d)*16];       // W[w][2d][2jj..2jj+1]
            float2 wb = wc[(2*d+1)*16];
            accx = fmaf(ax, wa.x, accx); accx = fmaf(ay, wb.x, accx);
            accy = fmaf(ax, wa.y, accy); accy = fmaf(ay, wb.y, accy);
        }
        if (lane < 48) {
            float ox = fmaxf(accx + bflo(zu), 0.f);
            float oy = fmaxf(accy + bfhi(zu), 0.f);
            *(uintT*)(rb2 + (size_t)t*96 + 2*pL) = pack2(ox, oy);
        }
    }
}

// ---------- layer 3: out = widthmean(relu(Lap(rb2)@W_post + Zpost)) ----------
// persistent: 3125 blocks x 4 iters; weights staged once per block
__global__ __launch_bounds__(256) void lap3(
    const ushortT* __restrict__ Xb,    // rb2 [N+1,96]
    const ushortT* __restrict__ Pb,    // Zpost = cols 288..479
    const int* __restrict__ src, const int* __restrict__ row_ptr,
    const float2* __restrict__ Wp2,    // [3][16][64] float2
    float* __restrict__ out)
{
    __shared__ float2 wS[3*16*64];
    __shared__ float  sm[4][96];       // per-wave activation slab (no barrier: wave DS in-order)
    for (int i = threadIdx.x; i < 3072; i += 256) wS[i] = Wp2[i];
    __syncthreads();

    int lane = threadIdx.x & 63;
    int wvw  = threadIdx.x >> 6;
    int pL = lane < 48 ? lane : 0;
    const float2* wl = wS + lane;      // step 64 float2 per (w,i2)

    #pragma unroll 1
    for (int it = 0; it < 4; ++it) {
        int t  = __builtin_amdgcn_readfirstlane(blockIdx.x*16 + it*4 + wvw);
        int lo = __builtin_amdgcn_readfirstlane(row_ptr[t]);
        int deg = __builtin_amdgcn_readfirstlane(row_ptr[t+1]) - lo;
        MAKE_SV(lo, deg, lane, 192, sv)
        uintT ux = *(const uintT*)(Xb + (size_t)t*96 + 2*pL);
        float z0 = bflo((uintT)Pb[(size_t)t*PCOLS + 288 + lane]);   // ch lane
        float z1 = bflo((uintT)Pb[(size_t)t*PCOLS + 352 + lane]);   // ch 64+lane
        float z2 = bflo((uintT)Pb[(size_t)t*PCOLS + 416 + lane]);   // ch 128+lane

        GATHER96(Xb, lo, deg, sv, pL, 192, sx, sy)

        float inv = deg > 0 ? 1.f/(float)deg : 0.f;
        float mf  = deg > 0 ? 1.f : 0.f;
        float Lx = mf*bflo(ux) - sx*inv;
        float Ly = mf*bfhi(ux) - sy*inv;

        // broadcast activations through per-wave LDS (uniform-address ds_read = broadcast)
        if (lane < 48) {
            sm[wvw][2*pL]     = Lx;
            sm[wvw][2*pL + 1] = Ly;
        }
        __builtin_amdgcn_wave_barrier();   // pin compiler order; wave DS ops are HW-in-order

        // conv: lane computes channels {L, 64+L, 128+L}
        float a0 = 0.f, a1 = 0.f, a2 = 0.f;
        #pragma unroll
        for (int w2 = 0; w2 < 3; ++w2) {
            float acc = 0.f;
            #pragma unroll
            for (int i2 = 0; i2 < 16; ++i2) {
                float2 iv = *(const float2*)(&sm[wvw][w2*32 + 2*i2]);   // broadcast read
                float2 p  = wl[(w2*16 + i2)*64];
                acc = fmaf(iv.x, p.x, acc);
                acc = fmaf(iv.y, p.y, acc);
            }
            if (w2 == 0) a0 = acc; else if (w2 == 1) a1 = acc; else a2 = acc;
        }
        __builtin_amdgcn_wave_barrier();   // reads done before next iter's sm writes

        float o0 = fmaxf(a0 + z0, 0.f);   // channel lane
        float o1 = fmaxf(a1 + z1, 0.f);   // channel 64+lane
        float o2 = fmaxf(a2 + z2, 0.f);   // channel 128+lane
        // width-mean: final[f] = (v(3f)+v(3f+1)+v(3f+2))/3, v(c) = o_{c>>6} @ lane c&63
        float r = 0.f;
        #pragma unroll
        for (int q = 0; q < 3; ++q) {
            int c = 3*lane + q;
            int sl = c & 63, wsel = c >> 6;
            float v0 = __shfl(o0, sl);
            float v1 = __shfl(o1, sl);
            float v2 = __shfl(o2, sl);
            r += (wsel == 0) ? v0 : ((wsel == 1) ? v1 : v2);
        }
        out[(size_t)t*64 + lane] = r * (1.0f/3.0f);
    }
}

extern "C" void kernel_launch(void* const* d_in, const int* in_sizes, int n_in,
                              void* d_out, int out_size, void* d_ws, size_t ws_size,
                              hipStream_t stream)
{
    const float* data    = (const float*)d_in[0];
    const int*   src     = (const int*)  d_in[1];
    const int*   tgt     = (const int*)  d_in[2];
    const float* W_pre   = (const float*)d_in[3];
    const float* b_pre   = (const float*)d_in[4];
    const float* T_pre   = (const float*)d_in[5];
    const float* bT_pre  = (const float*)d_in[6];
    const float* W_blk   = (const float*)d_in[7];
    const float* b_blk   = (const float*)d_in[8];   // cancels under Lap — unused
    const float* T_blk   = (const float*)d_in[9];
    const float* bT_blk  = (const float*)d_in[10];
    const float* W_post  = (const float*)d_in[11];
    const float* b_post  = (const float*)d_in[12];  // cancels under Lap — unused
    const float* T_post  = (const float*)d_in[13];
    const float* bT_post = (const float*)d_in[14];
    float* out = (float*)d_out;

    float*   ws      = (float*)d_ws;
    float*   bcat    = ws;                                   // 512 f32
    float2*  Wp2     = (float2*)(bcat + 512);                // 3*16*64 float2
    int*     row_ptr = (int*)(Wp2 + 3*16*64);                // 50008
    ushortT* Pb      = (ushortT*)(row_ptr + 50008);          // (N+1)*512 bf16
    ushortT* rb1     = Pb  + (size_t)(N_NODES+1) * PCOLS;    // (N+1)*96 bf16
    ushortT* rb2     = rb1 + (size_t)(N_NODES+1) * 96;       // (N+1)*96 bf16
    ushortT* Ab      = rb2 + (size_t)(N_NODES+1) * 96;       // N*128 bf16
    ushortT* Wb      = Ab  + (size_t)N_NODES * IN_F;         // 512*128 bf16

    prep1<<<(N_NODES*IN_F/8)/256, 256, 0, stream>>>(
        data, W_pre, b_pre, T_pre, bT_pre, T_blk, bT_blk, T_post, bT_post,
        W_post, tgt, Wb, bcat, Wp2, Ab, row_ptr, Pb, rb1, rb2);

    dim3 gg(PCOLS/128, (N_NODES + 127)/128);
    gemm_mfma<<<gg, 256, 0, stream>>>(Ab, Wb, bcat, Pb, N_NODES);

    lap1<<<N_NODES/4, 256, 0, stream>>>(Pb, src, row_ptr, rb1);
    lap2<<<N_NODES/16, 256, 0, stream>>>(rb1, Pb, src, row_ptr, W_blk, rb2);
    lap3<<<N_NODES/16, 256, 0, stream>>>(rb2, Pb, src, row_ptr, Wp2, out);
}

// Round 2
// 267.253 us; speedup vs baseline: 1.1355x; 1.0695x over previous
//
#include <hip/hip_runtime.h>
#include <cstdint>
#include <cstddef>

#define N_NODES 50000
#define E_EDGES 800000
#define IN_F    128
#define PCOLS   512   // Pb cols: [0,96) Y0 | [96,192) Zpre | [192,288) Zblk | [288,480) Zpost | pad

typedef unsigned short ushortT;
typedef unsigned int   uintT;
typedef __attribute__((ext_vector_type(8))) short s8v;   // 8 bf16 (4 VGPR)
typedef __attribute__((ext_vector_type(4))) float f4v;   // 4 fp32 acc
typedef __attribute__((ext_vector_type(2))) float f2v;   // packed fp32 pair (v_pk_add_f32 target)

__device__ __forceinline__ float bflo(uintT u){ union{uintT i;float f;}c; c.i=u<<16; return c.f; }
__device__ __forceinline__ float bfhi(uintT u){ union{uintT i;float f;}c; c.i=u&0xFFFF0000u; return c.f; }
__device__ __forceinline__ ushortT f2bfu(float f){
    union{float f;uintT u;}c; c.f=f;
    uintT r = c.u + 0x7FFF + ((c.u>>16)&1);
    return (ushortT)(r>>16);
}
__device__ __forceinline__ uintT pack2(float a, float b){
    return (uintT)f2bfu(a) | ((uintT)f2bfu(b) << 16);
}

// ---------- prep1: pack weights + convert data + row_ptr + dummy-row zero ----------
// grid = 800000 threads exactly (N*IN_F/8)
__global__ void prep1(const float* __restrict__ A,
                      const float* __restrict__ Wp,  const float* __restrict__ bp,
                      const float* __restrict__ Tp,  const float* __restrict__ bTp,
                      const float* __restrict__ Tb,  const float* __restrict__ bTb,
                      const float* __restrict__ Tpo, const float* __restrict__ bTpo,
                      const float* __restrict__ Wpost,
                      const int* __restrict__ tgt,
                      ushortT* __restrict__ Wb, float* __restrict__ bcat,
                      float2* __restrict__ Wp2,
                      ushortT* __restrict__ Ab, int* __restrict__ row_ptr,
                      ushortT* __restrict__ Pb, ushortT* __restrict__ rb1,
                      ushortT* __restrict__ rb2)
{
    int gid = blockIdx.x * 256 + threadIdx.x;
    {
        size_t off = (size_t)gid * 8;
        float4 v0 = *(const float4*)(A + off);
        float4 v1 = *(const float4*)(A + off + 4);
        uint4 u;
        u.x = pack2(v0.x, v0.y); u.y = pack2(v0.z, v0.w);
        u.z = pack2(v1.x, v1.y); u.w = pack2(v1.z, v1.w);
        *(uint4*)(Ab + off) = u;
    }
    if (gid < IN_F * PCOLS) {
        int k = gid >> 9;
        int c = gid & 511;
        float v;
        if      (c < 96)  v = Wp [k*96  + c];
        else if (c < 192) v = Tp [k*96  + (c-96)];
        else if (c < 288) v = Tb [k*96  + (c-192)];
        else if (c < 480) v = Tpo[k*192 + (c-288)];
        else              v = 0.f;
        Wb[(size_t)c*IN_F + k] = f2bfu(v);
        if (k == 0) {
            float b;
            if      (c < 96)  b = bp  [c];
            else if (c < 192) b = bTp [c-96];
            else if (c < 288) b = bTb [c-192];
            else if (c < 480) b = bTpo[c-288];
            else              b = 0.f;
            bcat[c] = b;
        }
        if (gid < 3*16*64) {   // Wp2[(w*16+i2)*64+j] = (Wpost[w][2i2][j], Wpost[w][2i2+1][j])
            int w = gid >> 10, r = gid & 1023;
            int i2 = r >> 6, j = r & 63;
            Wp2[gid] = make_float2(Wpost[(w*32 + 2*i2)*64 + j],
                                   Wpost[(w*32 + 2*i2 + 1)*64 + j]);
        }
    }
    if (gid < 96) {   // dummy gather row (node N) = 0 in every gather source
        Pb [(size_t)N_NODES*PCOLS + gid] = 0;
        rb1[(size_t)N_NODES*96   + gid] = 0;
        rb2[(size_t)N_NODES*96   + gid] = 0;
    }
    if (gid <= N_NODES) {
        int lo = 0, hi = E_EDGES;
        while (lo < hi) {
            int mid = (lo + hi) >> 1;
            if (tgt[mid] < gid) lo = mid + 1; else hi = mid;
        }
        row_ptr[gid] = lo;
    }
}

// ---------- MFMA GEMM: Pb[M,512] = bf16(Ab[M,128] @ Wb^T + bcat) ----------
// B tile (128 cols x K=128) staged ONCE in LDS; A fragments load direct from global
// (each A row read exactly once per block). Epilogue stages bf16 C through the same
// LDS buffer and writes fully-coalesced uint4 rows. XCD-swizzled grid: 8 XCDs x 49
// row-bands x 4 column-siblings; siblings adjacent on the same XCD -> A L2 reuse.
__global__ __launch_bounds__(256, 4) void gemm_mfma(const ushortT* __restrict__ Ab,
                                                    const ushortT* __restrict__ Wb,
                                                    const float* __restrict__ bcat,
                                                    ushortT* __restrict__ Pb, int M)
{
    __shared__ ushortT Bsl[128][136];   // 34816 B; B tile [n][k], reused as C staging
    int tid = threadIdx.x;
    int i = blockIdx.x;                  // 1568 = 8 * 49 * 4
    int xcd = i & 7, j = i >> 3;         // j in [0,196)
    int nb = (j & 3) * 128;              // column block
    int mb = (xcd * 49 + (j >> 2)) * 128;// row band 0..391 (tail bands OOB-guarded)
    int wv = tid >> 6, lane = tid & 63;
    int wm = wv >> 1, wn = wv & 1;
    int cl = lane & 15, q = lane >> 4;

    // stage whole B tile (128 cols x 128 k) once
    #pragma unroll
    for (int r = 0; r < 8; ++r) {
        int idx = tid + 256*r;
        int row = idx >> 4, qq = idx & 15;
        uint4 v = *(const uint4*)(Wb + (size_t)(nb+row)*IN_F + qq*8);
        *(uint4*)(&Bsl[row][qq*8]) = v;
    }
    __syncthreads();

    f4v acc[4][4];
    #pragma unroll
    for (int a = 0; a < 4; ++a)
        #pragma unroll
        for (int b = 0; b < 4; ++b) acc[a][b] = (f4v)0.f;

    int gmBase = mb + wm*64;
    #pragma unroll
    for (int ks = 0; ks < 4; ++ks) {
        int ko = ks*32 + q*8;
        s8v af[4], bf[4];
        #pragma unroll
        for (int mt = 0; mt < 4; ++mt) {
            int gm = gmBase + mt*16 + cl;
            uint4 va = make_uint4(0,0,0,0);
            if (gm < M) va = *(const uint4*)(Ab + (size_t)gm*IN_F + ko);
            af[mt] = *(s8v*)&va;
        }
        #pragma unroll
        for (int nt = 0; nt < 4; ++nt)
            bf[nt] = *(const s8v*)(&Bsl[wn*64 + nt*16 + cl][ko]);
        #pragma unroll
        for (int mt = 0; mt < 4; ++mt)
            #pragma unroll
            for (int nt = 0; nt < 4; ++nt)
                acc[mt][nt] = __builtin_amdgcn_mfma_f32_16x16x32_bf16(af[mt], bf[nt], acc[mt][nt], 0, 0, 0);
    }

    __syncthreads();   // all waves done reading Bsl -> reuse as C staging

    // bias + pack bf16 into LDS [row-in-tile][col-in-tile]
    #pragma unroll
    for (int nt = 0; nt < 4; ++nt) {
        int cn = wn*64 + nt*16 + cl;
        float bv = bcat[nb + cn];
        #pragma unroll
        for (int mt = 0; mt < 4; ++mt) {
            int rm0 = wm*64 + mt*16 + q*4;
            #pragma unroll
            for (int r = 0; r < 4; ++r)
                Bsl[rm0 + r][cn] = f2bfu(acc[mt][nt][r] + bv);
        }
    }
    __syncthreads();

    // coalesced write-out: 8 passes, each 16 rows x 256 B (2 full lines per row)
    #pragma unroll
    for (int p = 0; p < 8; ++p) {
        int idx = tid + 256*p;
        int row = idx >> 4, sg = idx & 15;
        int gm = mb + row;
        if (gm < M) {
            uint4 v = *(const uint4*)(&Bsl[row][sg*8]);
            *(uint4*)(Pb + (size_t)gm*PCOLS + nb + sg*8) = v;
        }
    }
}

// ===== gather core: 16-deep windows; scalar byte-offset addressing + packed adds =====
// sv holds PRE-SCALED byte offsets (row*STRB). (Xb + off) is wave-uniform -> saddr form;
// 4*pL is the per-lane constant voffset. STRB = gather-source row stride in BYTES.
#define GATHER96(Xb, lo, deg, sv, pL, STRB, sx, sy)                               \
    float sx, sy;                                                                 \
    {                                                                             \
        f2v c0={0.f,0.f}, c1={0.f,0.f}, c2={0.f,0.f}, c3={0.f,0.f};               \
        int dmax = deg < 64 ? deg : 64;                                           \
        _Pragma("unroll 1")                                                       \
        for (int w_ = 0; w_ < dmax; w_ += 16) {                                   \
            uintT u[16];                                                          \
            _Pragma("unroll")                                                     \
            for (int kk = 0; kk < 16; ++kk) {                                     \
                int off = __builtin_amdgcn_readlane(sv, w_ + kk);                 \
                const char* rp = (const char*)(Xb) + off;                         \
                u[kk] = *(const uintT*)(rp + 4*pL);                               \
            }                                                                     \
            _Pragma("unroll")                                                     \
            for (int kk = 0; kk < 16; ++kk) {                                     \
                f2v v_; v_.x = bflo(u[kk]); v_.y = bfhi(u[kk]);                   \
                switch (kk & 3) {                                                 \
                    case 0: c0 += v_; break;                                      \
                    case 1: c1 += v_; break;                                      \
                    case 2: c2 += v_; break;                                      \
                    default:c3 += v_; break;                                      \
                }                                                                 \
            }                                                                     \
        }                                                                         \
        if (deg > 64) {                                                           \
            _Pragma("unroll 1")                                                   \
            for (int j_ = lo + 64; j_ < lo + deg; ++j_) {                         \
                int off = src[j_] * (STRB);                                       \
                const char* rp = (const char*)(Xb) + off;                         \
                uintT u0 = *(const uintT*)(rp + 4*pL);                            \
                f2v v_; v_.x = bflo(u0); v_.y = bfhi(u0);                         \
                c0 += v_;                                                         \
            }                                                                     \
        }                                                                         \
        f2v cs_ = (c0 + c1) + (c2 + c3);                                          \
        sx = cs_.x; sy = cs_.y;                                                   \
    }

// per-lane gather slot from raw src: lane<deg ? src[lo+lane] : dummy row N
#define MAKE_SV(lo, deg, lane, STRB, sv)                                          \
    int sv;                                                                       \
    {                                                                             \
        int e_ = (lo) + (lane);                                                   \
        if (e_ > E_EDGES - 1) e_ = E_EDGES - 1;                                   \
        int sn_ = src[e_];                                                        \
        sv = ((lane) < (deg) ? sn_ : N_NODES) * (STRB);                           \
    }

// ---------- layer 1: rb1 = bf16(relu(Lap(Y0) + Zpre)), wave per node ----------
// own-x, Z and the gather all come from bf16 Pb (row stride 1024 B, cols 0..95 = Y0)
__global__ __launch_bounds__(256) void lap1(
    const ushortT* __restrict__ Pb,
    const int* __restrict__ src, const int* __restrict__ row_ptr,
    ushortT* __restrict__ rb1)
{
    int lane = threadIdx.x & 63;
    int t  = __builtin_amdgcn_readfirstlane((blockIdx.x << 2) + (threadIdx.x >> 6));
    int lo = __builtin_amdgcn_readfirstlane(row_ptr[t]);
    int deg = __builtin_amdgcn_readfirstlane(row_ptr[t+1]) - lo;
    int pL = lane < 48 ? lane : 0;
    MAKE_SV(lo, deg, lane, 2*PCOLS, sv)                    // Pb row = 1024 B
    uintT ux = *(const uintT*)(Pb + (size_t)t*PCOLS + 2*pL);        // Y0 cols 2pL,2pL+1
    uintT zu = *(const uintT*)(Pb + (size_t)t*PCOLS + 96 + 2*pL);   // Zpre

    GATHER96(Pb, lo, deg, sv, pL, 2*PCOLS, sx, sy)

    float inv = deg > 0 ? 1.f/(float)deg : 0.f;
    float mf  = deg > 0 ? 1.f : 0.f;
    if (lane < 48) {
        float ox = fmaxf(mf*bflo(ux) - sx*inv + bflo(zu), 0.f);
        float oy = fmaxf(mf*bfhi(ux) - sy*inv + bfhi(zu), 0.f);
        *(uintT*)(rb1 + (size_t)t*96 + 2*pL) = pack2(ox, oy);
    }
}

// ---------- layer 2: rb2 = bf16(relu(Lap(rb1)@W_blk + Zblk)) ----------
// persistent: 3125 blocks x 4 iters; weights staged once per block
__global__ __launch_bounds__(256) void lap2(
    const ushortT* __restrict__ Xb,    // rb1 [N+1,96]
    const ushortT* __restrict__ Pb,    // Zblk = cols 192..287
    const int* __restrict__ src, const int* __restrict__ row_ptr,
    const float* __restrict__ Wblk,    // [3][32][32] flat
    ushortT* __restrict__ rb2)
{
    __shared__ float wS[3*32*32];
    for (int i = threadIdx.x; i < 3072; i += 256) wS[i] = Wblk[i];
    __syncthreads();

    int lane = threadIdx.x & 63;
    int wvw  = threadIdx.x >> 6;
    int pL = lane < 48 ? lane : 0;
    int w  = pL >> 4;            // group (uniform per 16-lane slab)
    int jj = pL & 15;            // out pair index within group
    const float2* wc = ((const float2*)wS) + (w*512 + jj);   // &W[w][0][2jj]

    #pragma unroll 1
    for (int it = 0; it < 4; ++it) {
        int t  = __builtin_amdgcn_readfirstlane(blockIdx.x*16 + it*4 + wvw);
        int lo = __builtin_amdgcn_readfirstlane(row_ptr[t]);
        int deg = __builtin_amdgcn_readfirstlane(row_ptr[t+1]) - lo;
        MAKE_SV(lo, deg, lane, 192, sv)
        uintT ux = *(const uintT*)(Xb + (size_t)t*96 + 2*pL);
        uintT zu = *(const uintT*)(Pb + (size_t)t*PCOLS + 192 + 2*pL);

        GATHER96(Xb, lo, deg, sv, pL, 192, sx, sy)

        float inv = deg > 0 ? 1.f/(float)deg : 0.f;
        float mf  = deg > 0 ? 1.f : 0.f;
        float Lx = mf*bflo(ux) - sx*inv;    // Lap feat 2pL
        float Ly = mf*bfhi(ux) - sy*inv;    // Lap feat 2pL+1

        // conv (no bias): out channels (2pL, 2pL+1), inputs = group-w feats via shfl
        float accx = 0.f, accy = 0.f;
        #pragma unroll
        for (int d = 0; d < 16; ++d) {
            int sl = w*16 + d;
            float ax = __shfl(Lx, sl);      // feat 32w+2d
            float ay = __shfl(Ly, sl);      // feat 32w+2d+1
            float2 wa = wc[(2*d)*16];       // W[w][2d][2jj..2jj+1]
            float2 wb = wc[(2*d+1)*16];
            accx = fmaf(ax, wa.x, accx); accx = fmaf(ay, wb.x, accx);
            accy = fmaf(ax, wa.y, accy); accy = fmaf(ay, wb.y, accy);
        }
        if (lane < 48) {
            float ox = fmaxf(accx + bflo(zu), 0.f);
            float oy = fmaxf(accy + bfhi(zu), 0.f);
            *(uintT*)(rb2 + (size_t)t*96 + 2*pL) = pack2(ox, oy);
        }
    }
}

// ---------- layer 3: out = widthmean(relu(Lap(rb2)@W_post + Zpost)) ----------
// persistent: 3125 blocks x 4 iters; weights staged once per block
__global__ __launch_bounds__(256) void lap3(
    const ushortT* __restrict__ Xb,    // rb2 [N+1,96]
    const ushortT* __restrict__ Pb,    // Zpost = cols 288..479
    const int* __restrict__ src, const int* __restrict__ row_ptr,
    const float2* __restrict__ Wp2,    // [3][16][64] float2
    float* __restrict__ out)
{
    __shared__ float2 wS[3*16*64];
    __shared__ float  sm[4][96];       // per-wave activation slab (no barrier: wave DS in-order)
    for (int i = threadIdx.x; i < 3072; i += 256) wS[i] = Wp2[i];
    __syncthreads();

    int lane = threadIdx.x & 63;
    int wvw  = threadIdx.x >> 6;
    int pL = lane < 48 ? lane : 0;
    const float2* wl = wS + lane;      // step 64 float2 per (w,i2)

    #pragma unroll 1
    for (int it = 0; it < 4; ++it) {
        int t  = __builtin_amdgcn_readfirstlane(blockIdx.x*16 + it*4 + wvw);
        int lo = __builtin_amdgcn_readfirstlane(row_ptr[t]);
        int deg = __builtin_amdgcn_readfirstlane(row_ptr[t+1]) - lo;
        MAKE_SV(lo, deg, lane, 192, sv)
        uintT ux = *(const uintT*)(Xb + (size_t)t*96 + 2*pL);
        float z0 = bflo((uintT)Pb[(size_t)t*PCOLS + 288 + lane]);   // ch lane
        float z1 = bflo((uintT)Pb[(size_t)t*PCOLS + 352 + lane]);   // ch 64+lane
        float z2 = bflo((uintT)Pb[(size_t)t*PCOLS + 416 + lane]);   // ch 128+lane

        GATHER96(Xb, lo, deg, sv, pL, 192, sx, sy)

        float inv = deg > 0 ? 1.f/(float)deg : 0.f;
        float mf  = deg > 0 ? 1.f : 0.f;
        float Lx = mf*bflo(ux) - sx*inv;
        float Ly = mf*bfhi(ux) - sy*inv;

        // broadcast activations through per-wave LDS (uniform-address ds_read = broadcast)
        if (lane < 48) {
            sm[wvw][2*pL]     = Lx;
            sm[wvw][2*pL + 1] = Ly;
        }
        __builtin_amdgcn_wave_barrier();   // pin compiler order; wave DS ops are HW-in-order

        // conv: lane computes channels {L, 64+L, 128+L}
        float a0 = 0.f, a1 = 0.f, a2 = 0.f;
        #pragma unroll
        for (int w2 = 0; w2 < 3; ++w2) {
            float acc = 0.f;
            #pragma unroll
            for (int i2 = 0; i2 < 16; ++i2) {
                float2 iv = *(const float2*)(&sm[wvw][w2*32 + 2*i2]);   // broadcast read
                float2 p  = wl[(w2*16 + i2)*64];
                acc = fmaf(iv.x, p.x, acc);
                acc = fmaf(iv.y, p.y, acc);
            }
            if (w2 == 0) a0 = acc; else if (w2 == 1) a1 = acc; else a2 = acc;
        }
        __builtin_amdgcn_wave_barrier();   // reads done before next iter's sm writes

        float o0 = fmaxf(a0 + z0, 0.f);   // channel lane
        float o1 = fmaxf(a1 + z1, 0.f);   // channel 64+lane
        float o2 = fmaxf(a2 + z2, 0.f);   // channel 128+lane
        // width-mean: final[f] = (v(3f)+v(3f+1)+v(3f+2))/3, v(c) = o_{c>>6} @ lane c&63
        float r = 0.f;
        #pragma unroll
        for (int q = 0; q < 3; ++q) {
            int c = 3*lane + q;
            int sl = c & 63, wsel = c >> 6;
            float v0 = __shfl(o0, sl);
            float v1 = __shfl(o1, sl);
            float v2 = __shfl(o2, sl);
            r += (wsel == 0) ? v0 : ((wsel == 1) ? v1 : v2);
        }
        out[(size_t)t*64 + lane] = r * (1.0f/3.0f);
    }
}

extern "C" void kernel_launch(void* const* d_in, const int* in_sizes, int n_in,
                              void* d_out, int out_size, void* d_ws, size_t ws_size,
                              hipStream_t stream)
{
    const float* data    = (const float*)d_in[0];
    const int*   src     = (const int*)  d_in[1];
    const int*   tgt     = (const int*)  d_in[2];
    const float* W_pre   = (const float*)d_in[3];
    const float* b_pre   = (const float*)d_in[4];
    const float* T_pre   = (const float*)d_in[5];
    const float* bT_pre  = (const float*)d_in[6];
    const float* W_blk   = (const float*)d_in[7];
    const float* b_blk   = (const float*)d_in[8];   // cancels under Lap — unused
    const float* T_blk   = (const float*)d_in[9];
    const float* bT_blk  = (const float*)d_in[10];
    const float* W_post  = (const float*)d_in[11];
    const float* b_post  = (const float*)d_in[12];  // cancels under Lap — unused
    const float* T_post  = (const float*)d_in[13];
    const float* bT_post = (const float*)d_in[14];
    float* out = (float*)d_out;

    float*   ws      = (float*)d_ws;
    float*   bcat    = ws;                                   // 512 f32
    float2*  Wp2     = (float2*)(bcat + 512);                // 3*16*64 float2
    int*     row_ptr = (int*)(Wp2 + 3*16*64);                // 50008
    ushortT* Pb      = (ushortT*)(row_ptr + 50008);          // (N+1)*512 bf16
    ushortT* rb1     = Pb  + (size_t)(N_NODES+1) * PCOLS;    // (N+1)*96 bf16
    ushortT* rb2     = rb1 + (size_t)(N_NODES+1) * 96;       // (N+1)*96 bf16
    ushortT* Ab      = rb2 + (size_t)(N_NODES+1) * 96;       // N*128 bf16
    ushortT* Wb      = Ab  + (size_t)N_NODES * IN_F;         // 512*128 bf16

    prep1<<<(N_NODES*IN_F/8)/256, 256, 0, stream>>>(
        data, W_pre, b_pre, T_pre, bT_pre, T_blk, bT_blk, T_post, bT_post,
        W_post, tgt, Wb, bcat, Wp2, Ab, row_ptr, Pb, rb1, rb2);

    gemm_mfma<<<1568, 256, 0, stream>>>(Ab, Wb, bcat, Pb, N_NODES);

    lap1<<<N_NODES/4, 256, 0, stream>>>(Pb, src, row_ptr, rb1);
    lap2<<<N_NODES/16, 256, 0, stream>>>(rb1, Pb, src, row_ptr, W_blk, rb2);
    lap3<<<N_NODES/16, 256, 0, stream>>>(rb2, Pb, src, row_ptr, Wp2, out);
}